// Round 8
// baseline (592.173 us; speedup 1.0000x reference)
//
#include <hip/hip_runtime.h>
#include <math.h>

#define N_NODES  50000
#define N_EDGES  800000
#define E_TOT    (N_EDGES + N_NODES)   // 850000 incl self loops
#define N_GRAPHS 128
#define IN_F     768
#define HID2     128
#define NHID     64

typedef __attribute__((ext_vector_type(8))) short bf16x8;
typedef __attribute__((ext_vector_type(4))) float f32x4;

__device__ __forceinline__ float selu_f(float x) {
    const float alpha = 1.6732632423543772f;
    const float scale = 1.0507009873554805f;
    return scale * (x > 0.f ? x : alpha * (expf(x) - 1.f));
}

// round-to-nearest-even fp32 -> bf16
__device__ __forceinline__ unsigned short f2bf(float f) {
    unsigned u = __float_as_uint(f);
    u += 0x7FFFu + ((u >> 16) & 1u);
    return (unsigned short)(u >> 16);
}
__device__ __forceinline__ float bflo(unsigned q) { return __uint_as_float(q << 16); }
__device__ __forceinline__ float bfhi(unsigned q) { return __uint_as_float(q & 0xffff0000u); }

// ---------------- setup: zero deg + e-buffers, convert/transpose both weight matrices ----------------
__global__ void setup_k(const float* __restrict__ W1, const float* __restrict__ W2,
                        unsigned short* __restrict__ Wt1, unsigned short* __restrict__ Wt2,
                        unsigned* __restrict__ deg,
                        float* __restrict__ es1, float* __restrict__ ed1,
                        float* __restrict__ es2, float* __restrict__ ed2) {
    int i = blockIdx.x * blockDim.x + threadIdx.x;
    if (i < N_NODES) {
        deg[i] = 0u;
        es1[i] = 0.f; ed1[i] = 0.f;
        es2[i] = 0.f; ed2[i] = 0.f;
    }
    if (i < 128 * IN_F) {
        int n = i / IN_F, k = i - n * IN_F;
        Wt1[i] = f2bf(W1[(long)k * 128 + n]);
    }
    if (i < 128 * HID2) {
        int n = i >> 7, k = i & 127;
        Wt2[i] = f2bf(W2[(long)k * 128 + n]);
    }
}

// ---------------- GEMM: no-LDS direct-fragment MFMA + fused e_src/e_dst epilogue ----------------
// Each wave independently computes a 32x64 tile of C = A[Mx K] @ Bt^T (Bt: [128][K] bf16).
// A-frag (16B contiguous) and B-frag loaded straight from global; no __shared__, no barriers.
template<bool ABF16, bool OUTBF16>
__global__ __launch_bounds__(256, 4) void gemm_direct(
        const void* __restrict__ Av, const unsigned short* __restrict__ Bt,
        void* __restrict__ Cv, int M, int K,
        const float* __restrict__ a_s, const float* __restrict__ a_d,
        float* __restrict__ es, float* __restrict__ ed) {
    const float* Af = (const float*)Av;
    const unsigned short* Ab = (const unsigned short*)Av;
    const int tid  = threadIdx.x;
    const int row0 = blockIdx.x * 64;
    const int w    = tid >> 6;
    const int lane = tid & 63;
    const int quad = lane >> 4;
    const int l16  = lane & 15;
    const int m_off = (w & 1) * 32;   // wave covers 32 rows
    const int n_off = (w >> 1) * 64;  // x 64 cols

    // per-lane global base offsets for fragment loads
    long arow[2];
#pragma unroll
    for (int mi = 0; mi < 2; mi++) {
        int r = row0 + m_off + mi * 16 + l16;
        if (r > M - 1) r = M - 1;           // tail clamp; epilogue masks row>=M
        arow[mi] = (long)r * K + quad * 8;
    }
    long brow[4];
#pragma unroll
    for (int ni = 0; ni < 4; ni++)
        brow[ni] = (long)(n_off + ni * 16 + l16) * K + quad * 8;

    f32x4 acc[2][4];
#pragma unroll
    for (int mi = 0; mi < 2; mi++)
#pragma unroll
        for (int ni = 0; ni < 4; ni++)
            acc[mi][ni] = (f32x4){0.f, 0.f, 0.f, 0.f};

#define LOAD_A(dst, kk)                                                        \
    do {                                                                       \
        if (ABF16) {                                                           \
            _Pragma("unroll")                                                  \
            for (int mi = 0; mi < 2; mi++)                                     \
                dst[mi] = *(const bf16x8*)&Ab[arow[mi] + (kk)];                \
        } else {                                                               \
            _Pragma("unroll")                                                  \
            for (int mi = 0; mi < 2; mi++) {                                   \
                float4 v0 = *(const float4*)&Af[arow[mi] + (kk)];              \
                float4 v1 = *(const float4*)&Af[arow[mi] + (kk) + 4];          \
                bf16x8 o;                                                      \
                o[0] = (short)f2bf(v0.x); o[1] = (short)f2bf(v0.y);            \
                o[2] = (short)f2bf(v0.z); o[3] = (short)f2bf(v0.w);            \
                o[4] = (short)f2bf(v1.x); o[5] = (short)f2bf(v1.y);            \
                o[6] = (short)f2bf(v1.z); o[7] = (short)f2bf(v1.w);            \
                dst[mi] = o;                                                   \
            }                                                                  \
        }                                                                      \
    } while (0)

#define LOAD_B(dst, kk)                                                        \
    do {                                                                       \
        _Pragma("unroll")                                                      \
        for (int ni = 0; ni < 4; ni++)                                         \
            dst[ni] = *(const bf16x8*)&Bt[brow[ni] + (kk)];                    \
    } while (0)

#define MFMA_STEP(a, b)                                                        \
    do {                                                                       \
        _Pragma("unroll")                                                      \
        for (int mi = 0; mi < 2; mi++)                                         \
            _Pragma("unroll")                                                  \
            for (int ni = 0; ni < 4; ni++)                                     \
                acc[mi][ni] = __builtin_amdgcn_mfma_f32_16x16x32_bf16(         \
                    a[mi], b[ni], acc[mi][ni], 0, 0, 0);                       \
    } while (0)

    bf16x8 aP[2], bP[4], aQ[2], bQ[4];
    LOAD_A(aP, 0);
    LOAD_B(bP, 0);
    int k0 = 0;
    // ping-pong prefetch: next chunk's loads in flight while MFMAs run
    while (true) {
        if (k0 + 32 < K) { LOAD_A(aQ, k0 + 32); LOAD_B(bQ, k0 + 32); }
        MFMA_STEP(aP, bP);
        k0 += 32; if (k0 >= K) break;
        if (k0 + 32 < K) { LOAD_A(aP, k0 + 32); LOAD_B(bP, k0 + 32); }
        MFMA_STEP(aQ, bQ);
        k0 += 32; if (k0 >= K) break;
    }
#undef LOAD_A
#undef LOAD_B
#undef MFMA_STEP

    // attention-vector partials for this lane's 4 cols
    float as_v[4], ad_v[4];
#pragma unroll
    for (int ni = 0; ni < 4; ni++) {
        int col = n_off + ni * 16 + l16;
        as_v[ni] = a_s[col];
        ad_v[ni] = a_d[col];
    }

    // epilogue: D row = m_off+mi*16+quad*4+r, col = n_off+ni*16+l16
#pragma unroll
    for (int mi = 0; mi < 2; mi++)
#pragma unroll
        for (int r = 0; r < 4; r++) {
            int row = row0 + m_off + mi * 16 + quad * 4 + r;
            float ps = 0.f, pd = 0.f;
#pragma unroll
            for (int ni = 0; ni < 4; ni++) {
                float v = acc[mi][ni][r];
                ps = fmaf(v, as_v[ni], ps);
                pd = fmaf(v, ad_v[ni], pd);
            }
#pragma unroll
            for (int o = 1; o < 16; o <<= 1) {
                ps += __shfl_xor(ps, o);
                pd += __shfl_xor(pd, o);
            }
            if (row < M) {
                if (l16 == 0) {
                    atomicAdd(es + row, ps);
                    atomicAdd(ed + row, pd);
                }
                if (OUTBF16) {
                    unsigned short* C16 = (unsigned short*)Cv;
#pragma unroll
                    for (int ni = 0; ni < 4; ni++)
                        C16[(long)row * 128 + n_off + ni * 16 + l16] = f2bf(acc[mi][ni][r]);
                } else {
                    float* Cf = (float*)Cv;
#pragma unroll
                    for (int ni = 0; ni < 4; ni++)
                        Cf[(long)row * 128 + n_off + ni * 16 + l16] = acc[mi][ni][r];
                }
            }
        }
}

// ---------------- CSR build ----------------
__global__ void deg_hist(const int* __restrict__ ei, unsigned* __restrict__ deg) {
    int e = blockIdx.x * blockDim.x + threadIdx.x;
    if (e < N_EDGES) atomicAdd(&deg[ei[N_EDGES + e]], 1u);
}

// exclusive scan of (deg+1) -> row_ptr, fused with self-loop seed + cursor init.
__global__ __launch_bounds__(256) void scan_seed(const unsigned* __restrict__ deg,
                                                 unsigned* __restrict__ row_ptr,
                                                 unsigned* __restrict__ cursor,
                                                 unsigned* __restrict__ csr_src) {
    __shared__ unsigned psum_s[4];
    __shared__ unsigned wsum[4];
    int tid = threadIdx.x;
    int wid = tid >> 6, lane = tid & 63;
    int chunk0 = blockIdx.x * 256;

    unsigned psum = 0;
    for (int i = tid; i < chunk0; i += 256) psum += deg[i] + 1u;
    for (int o = 32; o; o >>= 1) psum += __shfl_xor(psum, o);
    if (lane == 0) psum_s[wid] = psum;

    int i = chunk0 + tid;
    unsigned v = (i < N_NODES) ? deg[i] + 1u : 0u;
    unsigned x = v;
    for (int o = 1; o < 64; o <<= 1) {
        unsigned y = __shfl_up(x, o);
        if (lane >= o) x += y;
    }
    if (lane == 63) wsum[wid] = x;
    __syncthreads();
    unsigned base = psum_s[0] + psum_s[1] + psum_s[2] + psum_s[3];
    unsigned wbase = 0;
    for (int k = 0; k < wid; k++) wbase += wsum[k];
    if (i < N_NODES) {
        unsigned rp = base + wbase + x - v;
        row_ptr[i] = rp;
        csr_src[rp] = (unsigned)i;   // self-loop first
        cursor[i] = rp + 1;
        if (i == N_NODES - 1) row_ptr[N_NODES] = rp + v;
    }
}

__global__ void csr_scatter(const int* __restrict__ ei,
                            unsigned* __restrict__ cursor, unsigned* __restrict__ csr_src) {
    int e = blockIdx.x * blockDim.x + threadIdx.x;
    if (e >= N_EDGES) return;
    int d = ei[N_EDGES + e];
    unsigned p = atomicAdd(&cursor[d], 1u);
    csr_src[p] = (unsigned)ei[e];
}

// ---------------- fused GAT tail: single edge pass, half-wave edge pairs ----------------
// wave per dst node; half-wave (32 lanes) per edge of a pair; lane covers features fl*4..fl*4+3
template<bool OUTBF16>
__global__ __launch_bounds__(256) void gat_agg(
        const unsigned* __restrict__ row_ptr, const unsigned* __restrict__ csr_src,
        const float* __restrict__ e_src, const float* __restrict__ e_dst,
        const unsigned short* __restrict__ xw, const float* __restrict__ bias,
        void* __restrict__ outv) {
    __shared__ float2 buf[4][64];     // (num, src-bits) per wave
    int wv = threadIdx.x >> 6;
    int node = blockIdx.x * 4 + wv;
    if (node >= N_NODES) return;
    int lane = threadIdx.x & 63;
    int half = lane >> 5;
    int fl   = lane & 31;
    unsigned beg = row_ptr[node], end = row_ptr[node + 1];
    int deg = (int)(end - beg);
    float ed = e_dst[node];
    const unsigned short* xwf = xw + fl * 4;

    float ax = 0.f, ay = 0.f, az = 0.f, aw = 0.f, den = 0.f;
    for (int base = 0; base < deg; base += 64) {
        int i = base + lane;
        float num = 0.f;
        unsigned s = 0u;
        if (i < deg) {
            s = csr_src[beg + i];
            float e = e_src[s] + ed;
            e = e > 0.f ? e : 0.2f * e;
            num = __expf(e);
            den += num;
        }
        float2 pk; pk.x = num; pk.y = __uint_as_float(s);
        buf[wv][lane] = pk;   // all 64 slots written (num=0 pad beyond deg)

        int cnt = deg - base; if (cnt > 64) cnt = 64;
        int steps = (cnt + 1) >> 1;   // edge pairs; this half takes edge 2t+half
        int t = 0;
        for (; t + 4 <= steps; t += 4) {
            float2 p0 = buf[wv][2 * (t + 0) + half];
            float2 p1 = buf[wv][2 * (t + 1) + half];
            float2 p2 = buf[wv][2 * (t + 2) + half];
            float2 p3 = buf[wv][2 * (t + 3) + half];
            uint2 q0 = *(const uint2*)&xwf[(long)__float_as_uint(p0.y) * HID2];
            uint2 q1 = *(const uint2*)&xwf[(long)__float_as_uint(p1.y) * HID2];
            uint2 q2 = *(const uint2*)&xwf[(long)__float_as_uint(p2.y) * HID2];
            uint2 q3 = *(const uint2*)&xwf[(long)__float_as_uint(p3.y) * HID2];
            ax = fmaf(p0.x, bflo(q0.x), ax); ay = fmaf(p0.x, bfhi(q0.x), ay);
            az = fmaf(p0.x, bflo(q0.y), az); aw = fmaf(p0.x, bfhi(q0.y), aw);
            ax = fmaf(p1.x, bflo(q1.x), ax); ay = fmaf(p1.x, bfhi(q1.x), ay);
            az = fmaf(p1.x, bflo(q1.y), az); aw = fmaf(p1.x, bfhi(q1.y), aw);
            ax = fmaf(p2.x, bflo(q2.x), ax); ay = fmaf(p2.x, bfhi(q2.x), ay);
            az = fmaf(p2.x, bflo(q2.y), az); aw = fmaf(p2.x, bfhi(q2.y), aw);
            ax = fmaf(p3.x, bflo(q3.x), ax); ay = fmaf(p3.x, bfhi(q3.x), ay);
            az = fmaf(p3.x, bflo(q3.y), az); aw = fmaf(p3.x, bfhi(q3.y), aw);
        }
        for (; t < steps; t++) {
            float2 p = buf[wv][2 * t + half];
            uint2 q = *(const uint2*)&xwf[(long)__float_as_uint(p.y) * HID2];
            ax = fmaf(p.x, bflo(q.x), ax); ay = fmaf(p.x, bfhi(q.x), ay);
            az = fmaf(p.x, bflo(q.y), az); aw = fmaf(p.x, bfhi(q.y), aw);
        }
    }
    // merge the two edge-parity halves; reduce den across all 64 lanes
    ax += __shfl_xor(ax, 32); ay += __shfl_xor(ay, 32);
    az += __shfl_xor(az, 32); aw += __shfl_xor(aw, 32);
    for (int o = 32; o; o >>= 1) den += __shfl_xor(den, o);
    float inv = 1.f / den;
    float v0 = selu_f(fmaf(ax, inv, bias[fl * 4 + 0]));
    float v1 = selu_f(fmaf(ay, inv, bias[fl * 4 + 1]));
    float v2 = selu_f(fmaf(az, inv, bias[fl * 4 + 2]));
    float v3 = selu_f(fmaf(aw, inv, bias[fl * 4 + 3]));
    if (half == 0) {
        if (OUTBF16) {
            uint2 o;
            o.x = ((unsigned)f2bf(v1) << 16) | (unsigned)f2bf(v0);
            o.y = ((unsigned)f2bf(v3) << 16) | (unsigned)f2bf(v2);
            *(uint2*)((unsigned short*)outv + (long)node * HID2 + fl * 4) = o;
        } else {
            float4 o = make_float4(v0, v1, v2, v3);
            *(float4*)((float*)outv + (long)node * HID2 + fl * 4) = o;
        }
    }
}

// ---------------- fused pool + fc1 + fc2 + log_softmax: one block per graph ----------------
__global__ __launch_bounds__(256) void pool_head(
        const float* __restrict__ h, const int* __restrict__ batch,
        const float* __restrict__ fc1w, const float* __restrict__ fc1b,
        const float* __restrict__ fc2w, const float* __restrict__ fc2b,
        float* __restrict__ out) {
    __shared__ float pooled_s[HID2];
    __shared__ float part[HID2];
    __shared__ float g_s[NHID];
    int g = blockIdx.x;
    int lo = 0, hi = N_NODES;
    while (lo < hi) { int mid = (lo + hi) >> 1; if (batch[mid] < g) lo = mid + 1; else hi = mid; }
    int start = lo;
    hi = N_NODES;
    while (lo < hi) { int mid = (lo + hi) >> 1; if (batch[mid] < g + 1) lo = mid + 1; else hi = mid; }
    int end = lo;

    int f = threadIdx.x & 127, half = threadIdx.x >> 7;
    float acc = 0.f;
    for (int n = start + half; n < end; n += 2) acc += h[(long)n * HID2 + f];
    if (half == 0) part[f] = acc;
    __syncthreads();
    if (half == 1) {
        float c = (float)(end - start);
        c = c > 1.f ? c : 1.f;
        pooled_s[f] = selu_f((part[f] + acc) / c);
    }
    __syncthreads();
    int j = threadIdx.x;
    if (j < NHID) {
        float a = fc1b[j];
#pragma unroll
        for (int k = 0; k < HID2; k++) a = fmaf(pooled_s[k], fc1w[k * NHID + j], a);
        g_s[j] = selu_f(a);
    }
    __syncthreads();
    if (j == 0) {
        float l0 = fc2b[0], l1 = fc2b[1];
#pragma unroll
        for (int k = 0; k < NHID; k++) {
            float v = g_s[k];
            l0 = fmaf(v, fc2w[2 * k + 0], l0);
            l1 = fmaf(v, fc2w[2 * k + 1], l1);
        }
        float m = fmaxf(l0, l1);
        float lse = m + logf(expf(l0 - m) + expf(l1 - m));
        out[g * 2 + 0] = l0 - lse;
        out[g * 2 + 1] = l1 - lse;
    }
}

extern "C" void kernel_launch(void* const* d_in, const int* in_sizes, int n_in,
                              void* d_out, int out_size, void* d_ws, size_t ws_size,
                              hipStream_t stream) {
    const float* x     = (const float*)d_in[0];
    const int*   ei    = (const int*)d_in[1];
    const int*   batch = (const int*)d_in[2];
    const float* W1    = (const float*)d_in[3];
    const float* as1   = (const float*)d_in[4];
    const float* ad1   = (const float*)d_in[5];
    const float* b1    = (const float*)d_in[6];
    const float* W2    = (const float*)d_in[7];
    const float* as2   = (const float*)d_in[8];
    const float* ad2   = (const float*)d_in[9];
    const float* b2    = (const float*)d_in[10];
    const float* fc1w  = (const float*)d_in[11];
    const float* fc1b  = (const float*)d_in[12];
    const float* fc2w  = (const float*)d_in[13];
    const float* fc2b  = (const float*)d_in[14];
    float* out = (float*)d_out;

    // workspace layout
    const long NH = (long)N_NODES * HID2;        // 6.4M elems
    unsigned short* xwb = (unsigned short*)d_ws;         // NH bf16 (xw, both layers)
    unsigned short* h1b = xwb + NH;                      // NH bf16 (h1)
    float*    B2      = (float*)(h1b + NH);              // NH f32 (h2, for pooling)
    float*    es1     = B2 + NH;
    float*    ed1     = es1 + N_NODES;
    float*    es2     = ed1 + N_NODES;
    float*    ed2     = es2 + N_NODES;
    unsigned* deg     = (unsigned*)(ed2 + N_NODES);
    unsigned* cursor  = deg + N_NODES;
    unsigned* row_ptr = cursor + N_NODES;               // N_NODES+1
    unsigned* csr_src = row_ptr + N_NODES + 1;          // E_TOT
    unsigned short* Wt1 = (unsigned short*)(csr_src + E_TOT);  // 128x768 bf16
    unsigned short* Wt2 = Wt1 + 128 * IN_F;                    // 128x128 bf16

    const int TB = 256;
    const int gNode = (N_NODES + TB - 1) / TB;
    const int gEdge = (N_EDGES + TB - 1) / TB;
    const int gGemm = (N_NODES + 63) / 64;
    const int gAgg  = (N_NODES + 3) / 4;

    // setup (zero deg + e-buffers, weight converts) + CSR build
    setup_k<<<(128 * IN_F + TB - 1) / TB, TB, 0, stream>>>(W1, W2, Wt1, Wt2, deg,
                                                           es1, ed1, es2, ed2);
    deg_hist<<<gEdge, TB, 0, stream>>>(ei, deg);
    scan_seed<<<gNode, TB, 0, stream>>>(deg, row_ptr, cursor, csr_src);
    csr_scatter<<<gEdge, TB, 0, stream>>>(ei, cursor, csr_src);

    // ---- layer 1 ----
    gemm_direct<false, true><<<gGemm, 256, 0, stream>>>(x, Wt1, xwb, N_NODES, IN_F,
                                                        as1, ad1, es1, ed1);
    gat_agg<true><<<gAgg, 256, 0, stream>>>(row_ptr, csr_src, es1, ed1, xwb, b1, h1b);

    // ---- layer 2 ----
    gemm_direct<true, true><<<gGemm, 256, 0, stream>>>(h1b, Wt2, xwb, N_NODES, HID2,
                                                       as2, ad2, es2, ed2);
    gat_agg<false><<<gAgg, 256, 0, stream>>>(row_ptr, csr_src, es2, ed2, xwb, b2, B2);

    // ---- pool + head (fused) ----
    pool_head<<<N_GRAPHS, 256, 0, stream>>>(B2, batch, fc1w, fc1b, fc2w, fc2b, out);
}